// Round 1
// baseline (527.112 us; speedup 1.0000x reference)
//
#include <hip/hip_runtime.h>
#include <hip/hip_bf16.h>
#include <stdint.h>

#define N_TOK 4096
#define HDIM  1024
#define DDIM  1024
#define NEXP  8
#define TWO_D 2048

typedef __bf16 bf16x8_t __attribute__((ext_vector_type(8)));
typedef float  f32x4_t  __attribute__((ext_vector_type(4)));

__device__ __forceinline__ void gload16(const void* g, void* l) {
  __builtin_amdgcn_global_load_lds(
      (const __attribute__((address_space(1))) void*)g,
      (__attribute__((address_space(3))) void*)l, 16, 0, 0);
}

// manual RNE float->bf16 (avoids __hip_bfloat16 union issues)
__device__ __forceinline__ uint16_t f2bf(float f) {
  union { float f; uint32_t u; } v; v.f = f;
  uint32_t r = ((v.u >> 16) & 1u) + 0x7fffu;
  return (uint16_t)((v.u + r) >> 16);
}

// ---------------- router: logits -> softmax -> top2 -> expert lists ----------------
__global__ __launch_bounds__(256) void router_kernel(
    const float* __restrict__ x, const float* __restrict__ gw,
    int* __restrict__ counts, int* __restrict__ tok_slot, float* __restrict__ slot_w) {
  int wid = threadIdx.x >> 6;
  int lane = threadIdx.x & 63;
  int t = blockIdx.x * 4 + wid;
  const float* xr = x + (size_t)t * HDIM;
  float acc[NEXP];
#pragma unroll
  for (int e = 0; e < NEXP; ++e) acc[e] = 0.f;
  for (int i = 0; i < HDIM / 64; ++i) {
    float xv = xr[lane + 64 * i];
#pragma unroll
    for (int e = 0; e < NEXP; ++e)
      acc[e] += xv * gw[e * HDIM + lane + 64 * i];
  }
#pragma unroll
  for (int off = 32; off > 0; off >>= 1) {
#pragma unroll
    for (int e = 0; e < NEXP; ++e)
      acc[e] += __shfl_xor(acc[e], off, 64);
  }
  if (lane == 0) {
    int e1 = 0; float l1 = acc[0];
#pragma unroll
    for (int e = 1; e < NEXP; ++e) if (acc[e] > l1) { l1 = acc[e]; e1 = e; }
    int e2 = -1; float l2 = -1e30f;
#pragma unroll
    for (int e = 0; e < NEXP; ++e) if (e != e1 && acc[e] > l2) { l2 = acc[e]; e2 = e; }
    float s = 0.f;
#pragma unroll
    for (int e = 0; e < NEXP; ++e) s += expf(acc[e] - l1);
    float p1 = 1.0f / s;
    float p2 = expf(l2 - l1) / s;
    float tw = p1 + p2 + 1e-9f;
    float w1 = p1 / tw, w2 = p2 / tw;
    float s2 = w1 + w2 + 1e-9f;
    w1 /= s2; w2 /= s2;
    int pos1 = atomicAdd(&counts[e1], 1);
    tok_slot[e1 * N_TOK + pos1] = 2 * t;
    slot_w[2 * t] = w1;
    int pos2 = atomicAdd(&counts[e2], 1);
    tok_slot[e2 * N_TOK + pos2] = 2 * t + 1;
    slot_w[2 * t + 1] = w2;
  }
}

// ---------------- x fp32 -> bf16 ----------------
__global__ __launch_bounds__(256) void cvt_x_kernel(const float* __restrict__ x,
                                                    uint16_t* __restrict__ xb) {
  int i = blockIdx.x * 256 + threadIdx.x;  // one float4 per thread
  float4 v = ((const float4*)x)[i];
  uint2 o;
  o.x = (uint32_t)f2bf(v.x) | ((uint32_t)f2bf(v.y) << 16);
  o.y = (uint32_t)f2bf(v.z) | ((uint32_t)f2bf(v.w) << 16);
  ((uint2*)xb)[i] = o;
}

// ---------------- transpose + convert: src fp32 [R][C] -> dst bf16 [C][R], per expert slice
__global__ __launch_bounds__(256) void transpose_cvt_kernel(
    const float* __restrict__ src, uint16_t* __restrict__ dst, int R, int C) {
  __shared__ float tile[32][33];
  size_t slice = (size_t)R * C;
  src += blockIdx.z * slice;
  dst += blockIdx.z * slice;
  int cb = blockIdx.x * 32, rbase = blockIdx.y * 32;
  int c = threadIdx.x & 31, r0 = threadIdx.x >> 5;
#pragma unroll
  for (int i = 0; i < 4; ++i) {
    int r = r0 + 8 * i;
    tile[r][c] = src[(size_t)(rbase + r) * C + cb + c];
  }
  __syncthreads();
  int r2 = (threadIdx.x & 15) * 2, cp0 = threadIdx.x >> 4;
#pragma unroll
  for (int i = 0; i < 2; ++i) {
    int cp = cp0 + 16 * i;
    uint32_t u = (uint32_t)f2bf(tile[r2][cp]) | ((uint32_t)f2bf(tile[r2 + 1][cp]) << 16);
    *(uint32_t*)(dst + (size_t)(cb + cp) * R + rbase + r2) = u;
  }
}

// ---------------- GEMM1: h = silu(x@Wg) * (x@Wu), gathered rows, fused epilogue ----------------
// tile 128 rows x 64 h-cols (128 B-cols: [gate 64 | up 64]); BK=32; 4 waves 2x2.
__global__ __launch_bounds__(256) void gemm_gu_kernel(
    const uint16_t* __restrict__ xb, const uint16_t* __restrict__ w1t,
    const int* __restrict__ counts, const int* __restrict__ tok_slot,
    uint16_t* __restrict__ h_buf) {
  int e = blockIdx.z;
  int M = counts[e];
  int rb = blockIdx.x;
  if (rb * 128 >= M) return;
  int c0 = blockIdx.y * 64;
  const int* list = tok_slot + e * N_TOK;
  const uint16_t* wB = w1t + (size_t)e * TWO_D * HDIM;

  __shared__ uint16_t As[128 * 32];
  __shared__ uint16_t Bs[128 * 32];

  int tid = threadIdx.x;
  int w = tid >> 6, l = tid & 63;
  int wr = w >> 1, wc = w & 1;
  int lane15 = l & 15, hi = l >> 4;

  const char* aSrc[2];
  const char* bSrc[2];
  char* aDst[2];
  char* bDst[2];
#pragma unroll
  for (int i = 0; i < 2; ++i) {
    int c = i * 4 + w;
    int r = c * 16 + (l >> 2);
    int pos = rb * 128 + r;
    if (pos > M - 1) pos = M - 1;
    int tok = list[pos] >> 1;
    aSrc[i] = (const char*)(xb + (size_t)tok * HDIM) + (l & 3) * 16;
    int bcol = (r < 64) ? (c0 + r) : (HDIM + c0 + (r - 64));
    bSrc[i] = (const char*)(wB + (size_t)bcol * HDIM) + (l & 3) * 16;
    aDst[i] = (char*)As + c * 1024;
    bDst[i] = (char*)Bs + c * 1024;
  }

  f32x4_t acc[4][4];
#pragma unroll
  for (int m = 0; m < 4; ++m)
#pragma unroll
    for (int n = 0; n < 4; ++n) acc[m][n] = {0.f, 0.f, 0.f, 0.f};

  uint32_t aOff[4], bOff[4];
#pragma unroll
  for (int m = 0; m < 4; ++m) aOff[m] = (uint32_t)((wr * 64 + m * 16 + lane15) * 64 + hi * 16);
#pragma unroll
  for (int n = 0; n < 4; ++n) {
    int bidx = (n < 2) ? (wc * 32 + n * 16 + lane15) : (64 + wc * 32 + (n - 2) * 16 + lane15);
    bOff[n] = (uint32_t)(bidx * 64 + hi * 16);
  }

#pragma unroll
  for (int i = 0; i < 2; ++i) { gload16(aSrc[i], aDst[i]); gload16(bSrc[i], bDst[i]); }

  for (int kt = 0; kt < HDIM / 32; ++kt) {
    __syncthreads();  // staged tile visible (syncthreads drains vmcnt)
    bf16x8_t a[4], b[4];
#pragma unroll
    for (int m = 0; m < 4; ++m) a[m] = *(const bf16x8_t*)((const char*)As + aOff[m]);
#pragma unroll
    for (int n = 0; n < 4; ++n) b[n] = *(const bf16x8_t*)((const char*)Bs + bOff[n]);
    __syncthreads();  // all reads done; LDS free for next stage
    if (kt + 1 < HDIM / 32) {
      int ko = (kt + 1) * 64;
#pragma unroll
      for (int i = 0; i < 2; ++i) { gload16(aSrc[i] + ko, aDst[i]); gload16(bSrc[i] + ko, bDst[i]); }
    }
#pragma unroll
    for (int m = 0; m < 4; ++m)
#pragma unroll
      for (int n = 0; n < 4; ++n)
        acc[m][n] = __builtin_amdgcn_mfma_f32_16x16x32_bf16(a[m], b[n], acc[m][n], 0, 0, 0);
  }

  int Mloc = M - rb * 128;
#pragma unroll
  for (int m = 0; m < 4; ++m) {
#pragma unroll
    for (int i = 0; i < 4; ++i) {
      int rl = wr * 64 + m * 16 + hi * 4 + i;
      if (rl < Mloc) {
        int slot = list[rb * 128 + rl];
        uint16_t* hr = h_buf + (size_t)slot * DDIM;
#pragma unroll
        for (int n = 0; n < 2; ++n) {
          int hcol = c0 + wc * 32 + n * 16 + lane15;
          float g = acc[m][n][i];
          float u = acc[m][n + 2][i];
          float hv = g / (1.f + expf(-g)) * u;
          hr[hcol] = f2bf(hv);
        }
      }
    }
  }
}

// ---------------- GEMM2: out += w * (h @ Wd), atomic scatter ----------------
__global__ __launch_bounds__(256) void gemm_down_kernel(
    const uint16_t* __restrict__ h_buf, const uint16_t* __restrict__ w2t,
    const int* __restrict__ counts, const int* __restrict__ tok_slot,
    const float* __restrict__ slot_w, float* __restrict__ out) {
  int e = blockIdx.z;
  int M = counts[e];
  int rb = blockIdx.x;
  if (rb * 128 >= M) return;
  int c0 = blockIdx.y * 128;
  const int* list = tok_slot + e * N_TOK;
  const uint16_t* wB = w2t + (size_t)e * HDIM * DDIM;

  __shared__ uint16_t As[128 * 32];
  __shared__ uint16_t Bs[128 * 32];

  int tid = threadIdx.x;
  int w = tid >> 6, l = tid & 63;
  int wr = w >> 1, wc = w & 1;
  int lane15 = l & 15, hi = l >> 4;

  const char* aSrc[2];
  const char* bSrc[2];
  char* aDst[2];
  char* bDst[2];
#pragma unroll
  for (int i = 0; i < 2; ++i) {
    int c = i * 4 + w;
    int r = c * 16 + (l >> 2);
    int pos = rb * 128 + r;
    if (pos > M - 1) pos = M - 1;
    int slot = list[pos];
    aSrc[i] = (const char*)(h_buf + (size_t)slot * DDIM) + (l & 3) * 16;
    bSrc[i] = (const char*)(wB + (size_t)(c0 + r) * DDIM) + (l & 3) * 16;
    aDst[i] = (char*)As + c * 1024;
    bDst[i] = (char*)Bs + c * 1024;
  }

  f32x4_t acc[4][4];
#pragma unroll
  for (int m = 0; m < 4; ++m)
#pragma unroll
    for (int n = 0; n < 4; ++n) acc[m][n] = {0.f, 0.f, 0.f, 0.f};

  uint32_t aOff[4], bOff[4];
#pragma unroll
  for (int m = 0; m < 4; ++m) aOff[m] = (uint32_t)((wr * 64 + m * 16 + lane15) * 64 + hi * 16);
#pragma unroll
  for (int n = 0; n < 4; ++n) bOff[n] = (uint32_t)((wc * 64 + n * 16 + lane15) * 64 + hi * 16);

#pragma unroll
  for (int i = 0; i < 2; ++i) { gload16(aSrc[i], aDst[i]); gload16(bSrc[i], bDst[i]); }

  for (int kt = 0; kt < DDIM / 32; ++kt) {
    __syncthreads();
    bf16x8_t a[4], b[4];
#pragma unroll
    for (int m = 0; m < 4; ++m) a[m] = *(const bf16x8_t*)((const char*)As + aOff[m]);
#pragma unroll
    for (int n = 0; n < 4; ++n) b[n] = *(const bf16x8_t*)((const char*)Bs + bOff[n]);
    __syncthreads();
    if (kt + 1 < DDIM / 32) {
      int ko = (kt + 1) * 64;
#pragma unroll
      for (int i = 0; i < 2; ++i) { gload16(aSrc[i] + ko, aDst[i]); gload16(bSrc[i] + ko, bDst[i]); }
    }
#pragma unroll
    for (int m = 0; m < 4; ++m)
#pragma unroll
      for (int n = 0; n < 4; ++n)
        acc[m][n] = __builtin_amdgcn_mfma_f32_16x16x32_bf16(a[m], b[n], acc[m][n], 0, 0, 0);
  }

  int Mloc = M - rb * 128;
#pragma unroll
  for (int m = 0; m < 4; ++m) {
#pragma unroll
    for (int i = 0; i < 4; ++i) {
      int rl = wr * 64 + m * 16 + hi * 4 + i;
      if (rl < Mloc) {
        int slot = list[rb * 128 + rl];
        int tok = slot >> 1;
        float wgt = slot_w[slot];
        float* orow = out + (size_t)tok * HDIM;
#pragma unroll
        for (int n = 0; n < 4; ++n) {
          int col = c0 + wc * 64 + n * 16 + lane15;
          atomicAdd(&orow[col], wgt * acc[m][n][i]);
        }
      }
    }
  }
}

extern "C" void kernel_launch(void* const* d_in, const int* in_sizes, int n_in,
                              void* d_out, int out_size, void* d_ws, size_t ws_size,
                              hipStream_t stream) {
  const float* x  = (const float*)d_in[0];
  const float* gw = (const float*)d_in[1];
  const float* w1 = (const float*)d_in[2];
  const float* w2 = (const float*)d_in[3];
  float* out = (float*)d_out;

  char* ws = (char*)d_ws;
  int*      counts   = (int*)ws;                       // [0, 1KB)
  int*      tok_slot = (int*)(ws + 1024);              // 8*4096*4 = 128KB
  float*    slot_w   = (float*)(ws + 1024 + 131072);   // 32KB
  size_t off = (size_t)1 << 20;
  uint16_t* xb  = (uint16_t*)(ws + off); off += (size_t)N_TOK * HDIM * 2;      // 8MB
  uint16_t* w1t = (uint16_t*)(ws + off); off += (size_t)NEXP * TWO_D * HDIM * 2; // 32MB
  uint16_t* w2t = (uint16_t*)(ws + off); off += (size_t)NEXP * HDIM * DDIM * 2;  // 16MB
  uint16_t* hb  = (uint16_t*)(ws + off); off += (size_t)2 * N_TOK * DDIM * 2;    // 16MB

  hipMemsetAsync(d_out, 0, (size_t)out_size * sizeof(float), stream);
  if (ws_size < off) return;  // clean failure signal: output stays zero

  hipMemsetAsync(counts, 0, 1024, stream);
  cvt_x_kernel<<<(N_TOK * HDIM) / 1024, 256, 0, stream>>>(x, xb);
  transpose_cvt_kernel<<<dim3(TWO_D / 32, HDIM / 32, NEXP), 256, 0, stream>>>(w1, w1t, HDIM, TWO_D);
  transpose_cvt_kernel<<<dim3(HDIM / 32, DDIM / 32, NEXP), 256, 0, stream>>>(w2, w2t, DDIM, HDIM);
  router_kernel<<<N_TOK / 4, 256, 0, stream>>>(x, gw, counts, tok_slot, slot_w);
  gemm_gu_kernel<<<dim3(32, 16, NEXP), 256, 0, stream>>>(xb, w1t, counts, tok_slot, hb);
  gemm_down_kernel<<<dim3(32, 8, NEXP), 256, 0, stream>>>(hb, w2t, counts, tok_slot, slot_w, out);
}

// Round 3
// 357.617 us; speedup vs baseline: 1.4740x; 1.4740x over previous
//
#include <hip/hip_runtime.h>
#include <hip/hip_bf16.h>
#include <stdint.h>

#define N_TOK 4096
#define HDIM  1024
#define DDIM  1024
#define NEXP  8
#define TWO_D 2048
#define BK    64

typedef __bf16 bf16x8_t __attribute__((ext_vector_type(8)));
typedef float  f32x4_t  __attribute__((ext_vector_type(4)));

__device__ __forceinline__ void gload16(const void* g, void* l) {
  __builtin_amdgcn_global_load_lds(
      (const __attribute__((address_space(1))) void*)g,
      (__attribute__((address_space(3))) void*)l, 16, 0, 0);
}

__device__ __forceinline__ uint16_t f2bf(float f) {
  union { float f; uint32_t u; } v; v.f = f;
  uint32_t r = ((v.u >> 16) & 1u) + 0x7fffu;
  return (uint16_t)((v.u + r) >> 16);
}

// ---------------- router ----------------
__global__ __launch_bounds__(256) void router_kernel(
    const float* __restrict__ x, const float* __restrict__ gw,
    int* __restrict__ counts, int* __restrict__ tok_slot, float* __restrict__ slot_w) {
  int wid = threadIdx.x >> 6;
  int lane = threadIdx.x & 63;
  int t = blockIdx.x * 4 + wid;
  const float* xr = x + (size_t)t * HDIM;
  float acc[NEXP];
#pragma unroll
  for (int e = 0; e < NEXP; ++e) acc[e] = 0.f;
  for (int i = 0; i < HDIM / 64; ++i) {
    float xv = xr[lane + 64 * i];
#pragma unroll
    for (int e = 0; e < NEXP; ++e)
      acc[e] += xv * gw[e * HDIM + lane + 64 * i];
  }
#pragma unroll
  for (int off = 32; off > 0; off >>= 1) {
#pragma unroll
    for (int e = 0; e < NEXP; ++e)
      acc[e] += __shfl_xor(acc[e], off, 64);
  }
  if (lane == 0) {
    int e1 = 0; float l1 = acc[0];
#pragma unroll
    for (int e = 1; e < NEXP; ++e) if (acc[e] > l1) { l1 = acc[e]; e1 = e; }
    int e2 = -1; float l2 = -1e30f;
#pragma unroll
    for (int e = 0; e < NEXP; ++e) if (e != e1 && acc[e] > l2) { l2 = acc[e]; e2 = e; }
    float s = 0.f;
#pragma unroll
    for (int e = 0; e < NEXP; ++e) s += expf(acc[e] - l1);
    float p1 = 1.0f / s;
    float p2 = expf(l2 - l1) / s;
    float tw = p1 + p2 + 1e-9f;
    float w1 = p1 / tw, w2 = p2 / tw;
    float s2 = w1 + w2 + 1e-9f;
    w1 /= s2; w2 /= s2;
    int pos1 = atomicAdd(&counts[e1], 1);
    tok_slot[e1 * N_TOK + pos1] = 2 * t;
    slot_w[2 * t] = w1;
    int pos2 = atomicAdd(&counts[e2], 1);
    tok_slot[e2 * N_TOK + pos2] = 2 * t + 1;
    slot_w[2 * t + 1] = w2;
  }
}

// ---------------- x fp32 -> bf16 ----------------
__global__ __launch_bounds__(256) void cvt_x_kernel(const float* __restrict__ x,
                                                    uint16_t* __restrict__ xb) {
  int i = blockIdx.x * 256 + threadIdx.x;
  float4 v = ((const float4*)x)[i];
  uint2 o;
  o.x = (uint32_t)f2bf(v.x) | ((uint32_t)f2bf(v.y) << 16);
  o.y = (uint32_t)f2bf(v.z) | ((uint32_t)f2bf(v.w) << 16);
  ((uint2*)xb)[i] = o;
}

// ---------------- transpose+cvt fp32 [R][C] -> bf16 [C][R] per expert ----------------
__global__ __launch_bounds__(256) void transpose_cvt_kernel(
    const float* __restrict__ src, uint16_t* __restrict__ dst, int R, int C) {
  __shared__ float tile[32][33];
  size_t slice = (size_t)R * C;
  src += blockIdx.z * slice;
  dst += blockIdx.z * slice;
  int cb = blockIdx.x * 32, rbase = blockIdx.y * 32;
  int c = threadIdx.x & 31, r0 = threadIdx.x >> 5;
#pragma unroll
  for (int i = 0; i < 4; ++i) {
    int r = r0 + 8 * i;
    tile[r][c] = src[(size_t)(rbase + r) * C + cb + c];
  }
  __syncthreads();
  int r2 = (threadIdx.x & 15) * 2, cp0 = threadIdx.x >> 4;
#pragma unroll
  for (int i = 0; i < 2; ++i) {
    int cp = cp0 + 16 * i;
    uint32_t u = (uint32_t)f2bf(tile[r2][cp]) | ((uint32_t)f2bf(tile[r2 + 1][cp]) << 16);
    *(uint32_t*)(dst + (size_t)(cb + cp) * R + rbase + r2) = u;
  }
}

// ---------------- GEMM1: 128 rows x 256 B-cols (128 h-cols), BK=64, 8 waves ----------------
__global__ __launch_bounds__(512) void gemm_gu_kernel(
    const uint16_t* __restrict__ xb, const uint16_t* __restrict__ w1t,
    const int* __restrict__ counts, const int* __restrict__ tok_slot,
    uint16_t* __restrict__ h_buf) {
  // grid 2048 = 8 experts x 32 rb x 8 cb ; XCD-bijective remap (chunk 256 = 1 expert/XCD)
  int id = blockIdx.x;
  id = (id & 7) * 256 + (id >> 3);
  int e = id >> 8;
  int rem = id & 255;
  int rb = rem >> 3;
  int cb = rem & 7;
  int M = counts[e];
  if (rb * 128 >= M) return;
  int c0 = cb * 128;  // h-col base
  const int* list = tok_slot + e * N_TOK;
  const uint16_t* wB = w1t + (size_t)e * TWO_D * HDIM;

  __shared__ uint16_t As[128 * BK];  // 16KB
  __shared__ uint16_t Bs[256 * BK];  // 32KB

  int tid = threadIdx.x;
  int w = tid >> 6, l = tid & 63;
  int wr = w >> 2, wc = w & 3;
  int lane15 = l & 15, hi = l >> 4;

  // staging: A 2 passes (64 rows each), B 4 passes (64 slots each); chunk-XOR pre-swizzled source
  const char* aSrc[2]; char* aDst[2];
#pragma unroll
  for (int p = 0; p < 2; ++p) {
    int row = p * 64 + (tid >> 3);
    int pos = rb * 128 + row; if (pos > M - 1) pos = M - 1;
    int tok = list[pos] >> 1;
    int kch = (tid & 7) ^ (row & 7);
    aSrc[p] = (const char*)(xb + (size_t)tok * HDIM) + kch * 16;
    aDst[p] = (char*)As + p * 8192 + tid * 16;
  }
  const char* bSrc[4]; char* bDst[4];
#pragma unroll
  for (int p = 0; p < 4; ++p) {
    int s = p * 64 + (tid >> 3);
    int j = s & 63, g = s >> 6;
    int col = (j < 32) ? (c0 + g * 32 + j) : (HDIM + c0 + g * 32 + (j - 32));
    int kch = (tid & 7) ^ (s & 7);
    bSrc[p] = (const char*)(wB + (size_t)col * HDIM) + kch * 16;
    bDst[p] = (char*)Bs + p * 8192 + tid * 16;
  }

  f32x4_t acc[4][4];
#pragma unroll
  for (int m = 0; m < 4; ++m)
#pragma unroll
    for (int n = 0; n < 4; ++n) acc[m][n] = {0.f, 0.f, 0.f, 0.f};

  uint32_t aRow[4], bRow[4], xch[2];
#pragma unroll
  for (int m = 0; m < 4; ++m) aRow[m] = (uint32_t)((wr * 64 + m * 16 + lane15) * 128);
#pragma unroll
  for (int n = 0; n < 4; ++n) bRow[n] = (uint32_t)((wc * 64 + n * 16 + lane15) * 128);
  xch[0] = (uint32_t)(((0 + hi) ^ (l & 7)) * 16);
  xch[1] = (uint32_t)(((4 + hi) ^ (l & 7)) * 16);

#pragma unroll
  for (int p = 0; p < 2; ++p) gload16(aSrc[p], aDst[p]);
#pragma unroll
  for (int p = 0; p < 4; ++p) gload16(bSrc[p], bDst[p]);

  for (int kt = 0; kt < HDIM / BK; ++kt) {
    __syncthreads();  // drains vmcnt: staged tile visible
    bf16x8_t a[2][4], b[2][4];
#pragma unroll
    for (int kk = 0; kk < 2; ++kk) {
#pragma unroll
      for (int m = 0; m < 4; ++m)
        a[kk][m] = *(const bf16x8_t*)((const char*)As + aRow[m] + xch[kk]);
#pragma unroll
      for (int n = 0; n < 4; ++n)
        b[kk][n] = *(const bf16x8_t*)((const char*)Bs + bRow[n] + xch[kk]);
    }
    __syncthreads();  // all reads done; LDS free
    if (kt + 1 < HDIM / BK) {
      int ko = (kt + 1) * 128;
#pragma unroll
      for (int p = 0; p < 2; ++p) gload16(aSrc[p] + ko, aDst[p]);
#pragma unroll
      for (int p = 0; p < 4; ++p) gload16(bSrc[p] + ko, bDst[p]);
    }
#pragma unroll
    for (int kk = 0; kk < 2; ++kk)
#pragma unroll
      for (int m = 0; m < 4; ++m)
#pragma unroll
        for (int n = 0; n < 4; ++n)
          acc[m][n] = __builtin_amdgcn_mfma_f32_16x16x32_bf16(a[kk][m], b[kk][n], acc[m][n], 0, 0, 0);
  }

  int Mloc = M - rb * 128;
#pragma unroll
  for (int m = 0; m < 4; ++m) {
#pragma unroll
    for (int i = 0; i < 4; ++i) {
      int rl = wr * 64 + m * 16 + hi * 4 + i;
      if (rl < Mloc) {
        int slot = list[rb * 128 + rl];
        uint16_t* hr = h_buf + (size_t)slot * DDIM;
#pragma unroll
        for (int n = 0; n < 2; ++n) {
          int hcol = c0 + wc * 32 + n * 16 + lane15;
          float g = acc[m][n][i];
          float u = acc[m][n + 2][i];
          float hv = g / (1.f + expf(-g)) * u;
          hr[hcol] = f2bf(hv);
        }
      }
    }
  }
}

// ---------------- GEMM2: 128 rows x 128 cols, BK=64, 4 waves ----------------
__global__ __launch_bounds__(256) void gemm_down_kernel(
    const uint16_t* __restrict__ h_buf, const uint16_t* __restrict__ w2t,
    const int* __restrict__ counts, const int* __restrict__ tok_slot,
    const float* __restrict__ slot_w, float* __restrict__ out) {
  int id = blockIdx.x;
  id = (id & 7) * 256 + (id >> 3);
  int e = id >> 8;
  int rem = id & 255;
  int rb = rem >> 3;
  int cb = rem & 7;
  int M = counts[e];
  if (rb * 128 >= M) return;
  int c0 = cb * 128;
  const int* list = tok_slot + e * N_TOK;
  const uint16_t* wB = w2t + (size_t)e * HDIM * DDIM;

  __shared__ uint16_t As[128 * BK];  // 16KB
  __shared__ uint16_t Bs[128 * BK];  // 16KB

  int tid = threadIdx.x;
  int w = tid >> 6, l = tid & 63;
  int wr = w >> 1, wc = w & 1;
  int lane15 = l & 15, hi = l >> 4;

  const char* aSrc[4]; char* aDst[4];
  const char* bSrc[4]; char* bDst[4];
#pragma unroll
  for (int p = 0; p < 4; ++p) {
    int row = p * 32 + (tid >> 3);
    int pos = rb * 128 + row; if (pos > M - 1) pos = M - 1;
    int slot = list[pos];
    int kch = (tid & 7) ^ (row & 7);
    aSrc[p] = (const char*)(h_buf + (size_t)slot * DDIM) + kch * 16;
    aDst[p] = (char*)As + p * 4096 + tid * 16;
    int col = c0 + row;
    bSrc[p] = (const char*)(wB + (size_t)col * DDIM) + kch * 16;
    bDst[p] = (char*)Bs + p * 4096 + tid * 16;
  }

  f32x4_t acc[4][4];
#pragma unroll
  for (int m = 0; m < 4; ++m)
#pragma unroll
    for (int n = 0; n < 4; ++n) acc[m][n] = {0.f, 0.f, 0.f, 0.f};

  uint32_t aRow[4], bRow[4], xch[2];
#pragma unroll
  for (int m = 0; m < 4; ++m) aRow[m] = (uint32_t)((wr * 64 + m * 16 + lane15) * 128);
#pragma unroll
  for (int n = 0; n < 4; ++n) bRow[n] = (uint32_t)((wc * 64 + n * 16 + lane15) * 128);
  xch[0] = (uint32_t)(((0 + hi) ^ (l & 7)) * 16);
  xch[1] = (uint32_t)(((4 + hi) ^ (l & 7)) * 16);

#pragma unroll
  for (int p = 0; p < 4; ++p) { gload16(aSrc[p], aDst[p]); gload16(bSrc[p], bDst[p]); }

  for (int kt = 0; kt < DDIM / BK; ++kt) {
    __syncthreads();
    bf16x8_t a[2][4], b[2][4];
#pragma unroll
    for (int kk = 0; kk < 2; ++kk) {
#pragma unroll
      for (int m = 0; m < 4; ++m)
        a[kk][m] = *(const bf16x8_t*)((const char*)As + aRow[m] + xch[kk]);
#pragma unroll
      for (int n = 0; n < 4; ++n)
        b[kk][n] = *(const bf16x8_t*)((const char*)Bs + bRow[n] + xch[kk]);
    }
    __syncthreads();
    if (kt + 1 < DDIM / BK) {
      int ko = (kt + 1) * 128;
#pragma unroll
      for (int p = 0; p < 4; ++p) { gload16(aSrc[p] + ko, aDst[p]); gload16(bSrc[p] + ko, bDst[p]); }
    }
#pragma unroll
    for (int kk = 0; kk < 2; ++kk)
#pragma unroll
      for (int m = 0; m < 4; ++m)
#pragma unroll
        for (int n = 0; n < 4; ++n)
          acc[m][n] = __builtin_amdgcn_mfma_f32_16x16x32_bf16(a[kk][m], b[kk][n], acc[m][n], 0, 0, 0);
  }

  int Mloc = M - rb * 128;
#pragma unroll
  for (int m = 0; m < 4; ++m) {
#pragma unroll
    for (int i = 0; i < 4; ++i) {
      int rl = wr * 64 + m * 16 + hi * 4 + i;
      if (rl < Mloc) {
        int slot = list[rb * 128 + rl];
        int tok = slot >> 1;
        float wgt = slot_w[slot];
        float* orow = out + (size_t)tok * HDIM;
#pragma unroll
        for (int n = 0; n < 4; ++n) {
          int col = c0 + wc * 64 + n * 16 + lane15;
          atomicAdd(&orow[col], wgt * acc[m][n][i]);
        }
      }
    }
  }
}

extern "C" void kernel_launch(void* const* d_in, const int* in_sizes, int n_in,
                              void* d_out, int out_size, void* d_ws, size_t ws_size,
                              hipStream_t stream) {
  const float* x  = (const float*)d_in[0];
  const float* gw = (const float*)d_in[1];
  const float* w1 = (const float*)d_in[2];
  const float* w2 = (const float*)d_in[3];
  float* out = (float*)d_out;

  char* ws = (char*)d_ws;
  int*      counts   = (int*)ws;
  int*      tok_slot = (int*)(ws + 1024);
  float*    slot_w   = (float*)(ws + 1024 + 131072);
  size_t off = (size_t)1 << 20;
  uint16_t* xb  = (uint16_t*)(ws + off); off += (size_t)N_TOK * HDIM * 2;
  uint16_t* w1t = (uint16_t*)(ws + off); off += (size_t)NEXP * TWO_D * HDIM * 2;
  uint16_t* w2t = (uint16_t*)(ws + off); off += (size_t)NEXP * HDIM * DDIM * 2;
  uint16_t* hb  = (uint16_t*)(ws + off); off += (size_t)2 * N_TOK * DDIM * 2;

  hipMemsetAsync(d_out, 0, (size_t)out_size * sizeof(float), stream);
  if (ws_size < off) return;

  hipMemsetAsync(counts, 0, 1024, stream);
  cvt_x_kernel<<<(N_TOK * HDIM) / 1024, 256, 0, stream>>>(x, xb);
  transpose_cvt_kernel<<<dim3(TWO_D / 32, HDIM / 32, NEXP), 256, 0, stream>>>(w1, w1t, HDIM, TWO_D);
  transpose_cvt_kernel<<<dim3(HDIM / 32, DDIM / 32, NEXP), 256, 0, stream>>>(w2, w2t, DDIM, HDIM);
  router_kernel<<<N_TOK / 4, 256, 0, stream>>>(x, gw, counts, tok_slot, slot_w);
  gemm_gu_kernel<<<2048, 512, 0, stream>>>(xb, w1t, counts, tok_slot, hb);
  gemm_down_kernel<<<2048, 256, 0, stream>>>(hb, w2t, counts, tok_slot, slot_w, out);
}

// Round 4
// 270.653 us; speedup vs baseline: 1.9476x; 1.3213x over previous
//
#include <hip/hip_runtime.h>
#include <hip/hip_bf16.h>
#include <stdint.h>

#define N_TOK 4096
#define HDIM  1024
#define DDIM  1024
#define NEXP  8
#define TWO_D 2048
#define BK    64

typedef __bf16 bf16x8_t __attribute__((ext_vector_type(8)));
typedef float  f32x4_t  __attribute__((ext_vector_type(4)));

__device__ __forceinline__ void gload16(const void* g, void* l) {
  __builtin_amdgcn_global_load_lds(
      (const __attribute__((address_space(1))) void*)g,
      (__attribute__((address_space(3))) void*)l, 16, 0, 0);
}

__device__ __forceinline__ uint16_t f2bf(float f) {
  union { float f; uint32_t u; } v; v.f = f;
  uint32_t r = ((v.u >> 16) & 1u) + 0x7fffu;
  return (uint16_t)((v.u + r) >> 16);
}

// ---------------- router A: logits -> softmax -> top2 (no atomics) ----------------
__global__ __launch_bounds__(256) void router_kernel(
    const float* __restrict__ x, const float* __restrict__ gw,
    uint32_t* __restrict__ t_e, float* __restrict__ slot_w) {
  int wid = threadIdx.x >> 6;
  int lane = threadIdx.x & 63;
  int t = blockIdx.x * 4 + wid;
  const float4* xr = (const float4*)(x + (size_t)t * HDIM);
  const float4* g4 = (const float4*)gw;
  float acc[NEXP];
#pragma unroll
  for (int e = 0; e < NEXP; ++e) acc[e] = 0.f;
#pragma unroll
  for (int i = 0; i < HDIM / 256; ++i) {
    float4 xv = xr[lane + 64 * i];
#pragma unroll
    for (int e = 0; e < NEXP; ++e) {
      float4 gv = g4[e * (HDIM / 4) + lane + 64 * i];
      acc[e] += xv.x * gv.x + xv.y * gv.y + xv.z * gv.z + xv.w * gv.w;
    }
  }
#pragma unroll
  for (int off = 32; off > 0; off >>= 1) {
#pragma unroll
    for (int e = 0; e < NEXP; ++e)
      acc[e] += __shfl_xor(acc[e], off, 64);
  }
  if (lane == 0) {
    int e1 = 0; float l1 = acc[0];
#pragma unroll
    for (int e = 1; e < NEXP; ++e) if (acc[e] > l1) { l1 = acc[e]; e1 = e; }
    int e2 = -1; float l2 = -1e30f;
#pragma unroll
    for (int e = 0; e < NEXP; ++e) if (e != e1 && acc[e] > l2) { l2 = acc[e]; e2 = e; }
    float s = 0.f;
#pragma unroll
    for (int e = 0; e < NEXP; ++e) s += expf(acc[e] - l1);
    float p1 = 1.0f / s;
    float p2 = expf(l2 - l1) / s;
    float tw = p1 + p2 + 1e-9f;
    float w1 = p1 / tw, w2 = p2 / tw;
    float s2 = w1 + w2 + 1e-9f;
    w1 /= s2; w2 /= s2;
    t_e[t] = (uint32_t)e1 | ((uint32_t)e2 << 16);
    slot_w[2 * t] = w1;
    slot_w[2 * t + 1] = w2;
  }
}

// ---------------- router B: build expert lists via LDS atomics (1 block) ----------------
__global__ __launch_bounds__(256) void build_lists_kernel(
    const uint32_t* __restrict__ t_e, int* __restrict__ counts,
    int* __restrict__ tok_slot) {
  __shared__ int cnt[NEXP];
  if (threadIdx.x < NEXP) cnt[threadIdx.x] = 0;
  __syncthreads();
  for (int t = threadIdx.x; t < N_TOK; t += 256) {
    uint32_t pe = t_e[t];
    int e1 = (int)(pe & 0xffffu), e2 = (int)(pe >> 16);
    int p1 = atomicAdd(&cnt[e1], 1);
    tok_slot[e1 * N_TOK + p1] = 2 * t;
    int p2 = atomicAdd(&cnt[e2], 1);
    tok_slot[e2 * N_TOK + p2] = 2 * t + 1;
  }
  __syncthreads();
  if (threadIdx.x < NEXP) counts[threadIdx.x] = cnt[threadIdx.x];
}

// ---------------- x fp32 -> bf16 ----------------
__global__ __launch_bounds__(256) void cvt_x_kernel(const float* __restrict__ x,
                                                    uint16_t* __restrict__ xb) {
  int i = blockIdx.x * 256 + threadIdx.x;
  float4 v = ((const float4*)x)[i];
  uint2 o;
  o.x = (uint32_t)f2bf(v.x) | ((uint32_t)f2bf(v.y) << 16);
  o.y = (uint32_t)f2bf(v.z) | ((uint32_t)f2bf(v.w) << 16);
  ((uint2*)xb)[i] = o;
}

// ---------------- transpose+cvt fp32 [R][C] -> bf16 [C][R] per expert ----------------
__global__ __launch_bounds__(256) void transpose_cvt_kernel(
    const float* __restrict__ src, uint16_t* __restrict__ dst, int R, int C) {
  __shared__ float tile[32][33];
  size_t slice = (size_t)R * C;
  src += blockIdx.z * slice;
  dst += blockIdx.z * slice;
  int cb = blockIdx.x * 32, rbase = blockIdx.y * 32;
  int c = threadIdx.x & 31, r0 = threadIdx.x >> 5;
#pragma unroll
  for (int i = 0; i < 4; ++i) {
    int r = r0 + 8 * i;
    tile[r][c] = src[(size_t)(rbase + r) * C + cb + c];
  }
  __syncthreads();
  int r2 = (threadIdx.x & 15) * 2, cp0 = threadIdx.x >> 4;
#pragma unroll
  for (int i = 0; i < 2; ++i) {
    int cp = cp0 + 16 * i;
    uint32_t u = (uint32_t)f2bf(tile[r2][cp]) | ((uint32_t)f2bf(tile[r2 + 1][cp]) << 16);
    *(uint32_t*)(dst + (size_t)(cb + cp) * R + rbase + r2) = u;
  }
}

// ---------------- GEMM1: 128 rows x 256 B-cols (128 h-cols), BK=64, 8 waves ----------------
__global__ __launch_bounds__(512) void gemm_gu_kernel(
    const uint16_t* __restrict__ xb, const uint16_t* __restrict__ w1t,
    const int* __restrict__ counts, const int* __restrict__ tok_slot,
    uint16_t* __restrict__ h_buf) {
  int id = blockIdx.x;
  id = (id & 7) * 256 + (id >> 3);
  int e = id >> 8;
  int rem = id & 255;
  int rb = rem >> 3;
  int cb = rem & 7;
  int M = counts[e];
  if (rb * 128 >= M) return;
  int c0 = cb * 128;
  const int* list = tok_slot + e * N_TOK;
  const uint16_t* wB = w1t + (size_t)e * TWO_D * HDIM;

  __shared__ uint16_t As[128 * BK];
  __shared__ uint16_t Bs[256 * BK];

  int tid = threadIdx.x;
  int w = tid >> 6, l = tid & 63;
  int wr = w >> 2, wc = w & 3;
  int lane15 = l & 15, hi = l >> 4;

  const char* aSrc[2]; char* aDst[2];
#pragma unroll
  for (int p = 0; p < 2; ++p) {
    int row = p * 64 + (tid >> 3);
    int pos = rb * 128 + row; if (pos > M - 1) pos = M - 1;
    int tok = list[pos] >> 1;
    int kch = (tid & 7) ^ (row & 7);
    aSrc[p] = (const char*)(xb + (size_t)tok * HDIM) + kch * 16;
    aDst[p] = (char*)As + p * 8192 + tid * 16;
  }
  const char* bSrc[4]; char* bDst[4];
#pragma unroll
  for (int p = 0; p < 4; ++p) {
    int s = p * 64 + (tid >> 3);
    int j = s & 63, g = s >> 6;
    int col = (j < 32) ? (c0 + g * 32 + j) : (HDIM + c0 + g * 32 + (j - 32));
    int kch = (tid & 7) ^ (s & 7);
    bSrc[p] = (const char*)(wB + (size_t)col * HDIM) + kch * 16;
    bDst[p] = (char*)Bs + p * 8192 + tid * 16;
  }

  f32x4_t acc[4][4];
#pragma unroll
  for (int m = 0; m < 4; ++m)
#pragma unroll
    for (int n = 0; n < 4; ++n) acc[m][n] = {0.f, 0.f, 0.f, 0.f};

  uint32_t aRow[4], bRow[4], xch[2];
#pragma unroll
  for (int m = 0; m < 4; ++m) aRow[m] = (uint32_t)((wr * 64 + m * 16 + lane15) * 128);
#pragma unroll
  for (int n = 0; n < 4; ++n) bRow[n] = (uint32_t)((wc * 64 + n * 16 + lane15) * 128);
  xch[0] = (uint32_t)(((0 + hi) ^ (l & 7)) * 16);
  xch[1] = (uint32_t)(((4 + hi) ^ (l & 7)) * 16);

#pragma unroll
  for (int p = 0; p < 2; ++p) gload16(aSrc[p], aDst[p]);
#pragma unroll
  for (int p = 0; p < 4; ++p) gload16(bSrc[p], bDst[p]);

  for (int kt = 0; kt < HDIM / BK; ++kt) {
    __syncthreads();
    bf16x8_t a[2][4], b[2][4];
#pragma unroll
    for (int kk = 0; kk < 2; ++kk) {
#pragma unroll
      for (int m = 0; m < 4; ++m)
        a[kk][m] = *(const bf16x8_t*)((const char*)As + aRow[m] + xch[kk]);
#pragma unroll
      for (int n = 0; n < 4; ++n)
        b[kk][n] = *(const bf16x8_t*)((const char*)Bs + bRow[n] + xch[kk]);
    }
    __syncthreads();
    if (kt + 1 < HDIM / BK) {
      int ko = (kt + 1) * 128;
#pragma unroll
      for (int p = 0; p < 2; ++p) gload16(aSrc[p] + ko, aDst[p]);
#pragma unroll
      for (int p = 0; p < 4; ++p) gload16(bSrc[p] + ko, bDst[p]);
    }
#pragma unroll
    for (int kk = 0; kk < 2; ++kk)
#pragma unroll
      for (int m = 0; m < 4; ++m)
#pragma unroll
        for (int n = 0; n < 4; ++n)
          acc[m][n] = __builtin_amdgcn_mfma_f32_16x16x32_bf16(a[kk][m], b[kk][n], acc[m][n], 0, 0, 0);
  }

  int Mloc = M - rb * 128;
#pragma unroll
  for (int m = 0; m < 4; ++m) {
#pragma unroll
    for (int i = 0; i < 4; ++i) {
      int rl = wr * 64 + m * 16 + hi * 4 + i;
      if (rl < Mloc) {
        int slot = list[rb * 128 + rl];
        uint16_t* hr = h_buf + (size_t)slot * DDIM;
#pragma unroll
        for (int n = 0; n < 2; ++n) {
          int hcol = c0 + wc * 32 + n * 16 + lane15;
          float g = acc[m][n][i];
          float u = acc[m][n + 2][i];
          float hv = g / (1.f + expf(-g)) * u;
          hr[hcol] = f2bf(hv);
        }
      }
    }
  }
}

// ---------------- GEMM2: 128 rows x 128 cols, BK=64, 4 waves ----------------
__global__ __launch_bounds__(256) void gemm_down_kernel(
    const uint16_t* __restrict__ h_buf, const uint16_t* __restrict__ w2t,
    const int* __restrict__ counts, const int* __restrict__ tok_slot,
    const float* __restrict__ slot_w, float* __restrict__ out) {
  int id = blockIdx.x;
  id = (id & 7) * 256 + (id >> 3);
  int e = id >> 8;
  int rem = id & 255;
  int rb = rem >> 3;
  int cb = rem & 7;
  int M = counts[e];
  if (rb * 128 >= M) return;
  int c0 = cb * 128;
  const int* list = tok_slot + e * N_TOK;
  const uint16_t* wB = w2t + (size_t)e * HDIM * DDIM;

  __shared__ uint16_t As[128 * BK];
  __shared__ uint16_t Bs[128 * BK];

  int tid = threadIdx.x;
  int w = tid >> 6, l = tid & 63;
  int wr = w >> 1, wc = w & 1;
  int lane15 = l & 15, hi = l >> 4;

  const char* aSrc[4]; char* aDst[4];
  const char* bSrc[4]; char* bDst[4];
#pragma unroll
  for (int p = 0; p < 4; ++p) {
    int row = p * 32 + (tid >> 3);
    int pos = rb * 128 + row; if (pos > M - 1) pos = M - 1;
    int slot = list[pos];
    int kch = (tid & 7) ^ (row & 7);
    aSrc[p] = (const char*)(h_buf + (size_t)slot * DDIM) + kch * 16;
    aDst[p] = (char*)As + p * 4096 + tid * 16;
    int col = c0 + row;
    bSrc[p] = (const char*)(wB + (size_t)col * DDIM) + kch * 16;
    bDst[p] = (char*)Bs + p * 4096 + tid * 16;
  }

  f32x4_t acc[4][4];
#pragma unroll
  for (int m = 0; m < 4; ++m)
#pragma unroll
    for (int n = 0; n < 4; ++n) acc[m][n] = {0.f, 0.f, 0.f, 0.f};

  uint32_t aRow[4], bRow[4], xch[2];
#pragma unroll
  for (int m = 0; m < 4; ++m) aRow[m] = (uint32_t)((wr * 64 + m * 16 + lane15) * 128);
#pragma unroll
  for (int n = 0; n < 4; ++n) bRow[n] = (uint32_t)((wc * 64 + n * 16 + lane15) * 128);
  xch[0] = (uint32_t)(((0 + hi) ^ (l & 7)) * 16);
  xch[1] = (uint32_t)(((4 + hi) ^ (l & 7)) * 16);

#pragma unroll
  for (int p = 0; p < 4; ++p) { gload16(aSrc[p], aDst[p]); gload16(bSrc[p], bDst[p]); }

  for (int kt = 0; kt < DDIM / BK; ++kt) {
    __syncthreads();
    bf16x8_t a[2][4], b[2][4];
#pragma unroll
    for (int kk = 0; kk < 2; ++kk) {
#pragma unroll
      for (int m = 0; m < 4; ++m)
        a[kk][m] = *(const bf16x8_t*)((const char*)As + aRow[m] + xch[kk]);
#pragma unroll
      for (int n = 0; n < 4; ++n)
        b[kk][n] = *(const bf16x8_t*)((const char*)Bs + bRow[n] + xch[kk]);
    }
    __syncthreads();
    if (kt + 1 < DDIM / BK) {
      int ko = (kt + 1) * 128;
#pragma unroll
      for (int p = 0; p < 4; ++p) { gload16(aSrc[p] + ko, aDst[p]); gload16(bSrc[p] + ko, bDst[p]); }
    }
#pragma unroll
    for (int kk = 0; kk < 2; ++kk)
#pragma unroll
      for (int m = 0; m < 4; ++m)
#pragma unroll
        for (int n = 0; n < 4; ++n)
          acc[m][n] = __builtin_amdgcn_mfma_f32_16x16x32_bf16(a[kk][m], b[kk][n], acc[m][n], 0, 0, 0);
  }

  int Mloc = M - rb * 128;
#pragma unroll
  for (int m = 0; m < 4; ++m) {
#pragma unroll
    for (int i = 0; i < 4; ++i) {
      int rl = wr * 64 + m * 16 + hi * 4 + i;
      if (rl < Mloc) {
        int slot = list[rb * 128 + rl];
        int tok = slot >> 1;
        float wgt = slot_w[slot];
        float* orow = out + (size_t)tok * HDIM;
#pragma unroll
        for (int n = 0; n < 4; ++n) {
          int col = c0 + wc * 64 + n * 16 + lane15;
          atomicAdd(&orow[col], wgt * acc[m][n][i]);
        }
      }
    }
  }
}

extern "C" void kernel_launch(void* const* d_in, const int* in_sizes, int n_in,
                              void* d_out, int out_size, void* d_ws, size_t ws_size,
                              hipStream_t stream) {
  const float* x  = (const float*)d_in[0];
  const float* gw = (const float*)d_in[1];
  const float* w1 = (const float*)d_in[2];
  const float* w2 = (const float*)d_in[3];
  float* out = (float*)d_out;

  char* ws = (char*)d_ws;
  int*      counts   = (int*)ws;                               // 1 KB
  int*      tok_slot = (int*)(ws + 1024);                      // 128 KB
  float*    slot_w   = (float*)(ws + 1024 + 131072);           // 32 KB
  uint32_t* t_e      = (uint32_t*)(ws + 1024 + 131072 + 32768);// 16 KB
  size_t off = (size_t)1 << 20;
  uint16_t* xb  = (uint16_t*)(ws + off); off += (size_t)N_TOK * HDIM * 2;
  uint16_t* w1t = (uint16_t*)(ws + off); off += (size_t)NEXP * TWO_D * HDIM * 2;
  uint16_t* w2t = (uint16_t*)(ws + off); off += (size_t)NEXP * HDIM * DDIM * 2;
  uint16_t* hb  = (uint16_t*)(ws + off); off += (size_t)2 * N_TOK * DDIM * 2;

  hipMemsetAsync(d_out, 0, (size_t)out_size * sizeof(float), stream);
  if (ws_size < off) return;

  cvt_x_kernel<<<(N_TOK * HDIM) / 1024, 256, 0, stream>>>(x, xb);
  transpose_cvt_kernel<<<dim3(TWO_D / 32, HDIM / 32, NEXP), 256, 0, stream>>>(w1, w1t, HDIM, TWO_D);
  transpose_cvt_kernel<<<dim3(HDIM / 32, DDIM / 32, NEXP), 256, 0, stream>>>(w2, w2t, DDIM, HDIM);
  router_kernel<<<N_TOK / 4, 256, 0, stream>>>(x, gw, t_e, slot_w);
  build_lists_kernel<<<1, 256, 0, stream>>>(t_e, counts, tok_slot);
  gemm_gu_kernel<<<2048, 512, 0, stream>>>(xb, w1t, counts, tok_slot, hb);
  gemm_down_kernel<<<2048, 256, 0, stream>>>(hb, w2t, counts, tok_slot, slot_w, out);
}

// Round 7
// 257.943 us; speedup vs baseline: 2.0435x; 1.0493x over previous
//
#include <hip/hip_runtime.h>
#include <hip/hip_bf16.h>
#include <stdint.h>

#define N_TOK 4096
#define HDIM  1024
#define DDIM  1024
#define NEXP  8
#define TWO_D 2048
#define BK    64

typedef __bf16 bf16x8_t __attribute__((ext_vector_type(8)));
typedef float  f32x4_t  __attribute__((ext_vector_type(4)));

__device__ __forceinline__ void gload16(const void* g, void* l) {
  __builtin_amdgcn_global_load_lds(
      (const __attribute__((address_space(1))) void*)g,
      (__attribute__((address_space(3))) void*)l, 16, 0, 0);
}

__device__ __forceinline__ uint16_t f2bf(float f) {
  union { float f; uint32_t u; } v; v.f = f;
  uint32_t r = ((v.u >> 16) & 1u) + 0x7fffu;
  return (uint16_t)((v.u + r) >> 16);
}

__device__ __forceinline__ float bf2f(uint16_t b) {
  union { uint32_t u; float f; } v; v.u = (uint32_t)b << 16;
  return v.f;
}

// ---------------- router A: logits -> softmax -> top2 (no atomics) ----------------
__global__ __launch_bounds__(256) void router_kernel(
    const float* __restrict__ x, const float* __restrict__ gw,
    uint32_t* __restrict__ t_e, float* __restrict__ slot_w) {
  int wid = threadIdx.x >> 6;
  int lane = threadIdx.x & 63;
  int t = blockIdx.x * 4 + wid;
  const float4* xr = (const float4*)(x + (size_t)t * HDIM);
  const float4* g4 = (const float4*)gw;
  float acc[NEXP];
#pragma unroll
  for (int e = 0; e < NEXP; ++e) acc[e] = 0.f;
#pragma unroll
  for (int i = 0; i < HDIM / 256; ++i) {
    float4 xv = xr[lane + 64 * i];
#pragma unroll
    for (int e = 0; e < NEXP; ++e) {
      float4 gv = g4[e * (HDIM / 4) + lane + 64 * i];
      acc[e] += xv.x * gv.x + xv.y * gv.y + xv.z * gv.z + xv.w * gv.w;
    }
  }
#pragma unroll
  for (int off = 32; off > 0; off >>= 1) {
#pragma unroll
    for (int e = 0; e < NEXP; ++e)
      acc[e] += __shfl_xor(acc[e], off, 64);
  }
  if (lane == 0) {
    int e1 = 0; float l1 = acc[0];
#pragma unroll
    for (int e = 1; e < NEXP; ++e) if (acc[e] > l1) { l1 = acc[e]; e1 = e; }
    int e2 = -1; float l2 = -1e30f;
#pragma unroll
    for (int e = 0; e < NEXP; ++e) if (e != e1 && acc[e] > l2) { l2 = acc[e]; e2 = e; }
    float s = 0.f;
#pragma unroll
    for (int e = 0; e < NEXP; ++e) s += expf(acc[e] - l1);
    float p1 = 1.0f / s;
    float p2 = expf(l2 - l1) / s;
    float tw = p1 + p2 + 1e-9f;
    float w1 = p1 / tw, w2 = p2 / tw;
    float s2 = w1 + w2 + 1e-9f;
    w1 /= s2; w2 /= s2;
    t_e[t] = (uint32_t)e1 | ((uint32_t)e2 << 16);
    slot_w[2 * t] = w1;
    slot_w[2 * t + 1] = w2;
  }
}

// ---------------- router B: build expert lists via LDS atomics (1 block) ----------------
__global__ __launch_bounds__(256) void build_lists_kernel(
    const uint32_t* __restrict__ t_e, int* __restrict__ counts,
    int* __restrict__ tok_slot) {
  __shared__ int cnt[NEXP];
  if (threadIdx.x < NEXP) cnt[threadIdx.x] = 0;
  __syncthreads();
  for (int t = threadIdx.x; t < N_TOK; t += 256) {
    uint32_t pe = t_e[t];
    int e1 = (int)(pe & 0xffffu), e2 = (int)(pe >> 16);
    int p1 = atomicAdd(&cnt[e1], 1);
    tok_slot[e1 * N_TOK + p1] = 2 * t;
    int p2 = atomicAdd(&cnt[e2], 1);
    tok_slot[e2 * N_TOK + p2] = 2 * t + 1;
  }
  __syncthreads();
  if (threadIdx.x < NEXP) counts[threadIdx.x] = cnt[threadIdx.x];
}

// ---------------- x fp32 -> bf16 ----------------
__global__ __launch_bounds__(256) void cvt_x_kernel(const float* __restrict__ x,
                                                    uint16_t* __restrict__ xb) {
  int i = blockIdx.x * 256 + threadIdx.x;
  float4 v = ((const float4*)x)[i];
  uint2 o;
  o.x = (uint32_t)f2bf(v.x) | ((uint32_t)f2bf(v.y) << 16);
  o.y = (uint32_t)f2bf(v.z) | ((uint32_t)f2bf(v.w) << 16);
  ((uint2*)xb)[i] = o;
}

// ---------------- transpose+cvt fp32 [R][C] -> bf16 [C][R] per expert ----------------
__global__ __launch_bounds__(256) void transpose_cvt_kernel(
    const float* __restrict__ src, uint16_t* __restrict__ dst, int R, int C) {
  __shared__ float tile[32][33];
  size_t slice = (size_t)R * C;
  src += blockIdx.z * slice;
  dst += blockIdx.z * slice;
  int cb = blockIdx.x * 32, rbase = blockIdx.y * 32;
  int c = threadIdx.x & 31, r0 = threadIdx.x >> 5;
#pragma unroll
  for (int i = 0; i < 4; ++i) {
    int r = r0 + 8 * i;
    tile[r][c] = src[(size_t)(rbase + r) * C + cb + c];
  }
  __syncthreads();
  int r2 = (threadIdx.x & 15) * 2, cp0 = threadIdx.x >> 4;
#pragma unroll
  for (int i = 0; i < 2; ++i) {
    int cp = cp0 + 16 * i;
    uint32_t u = (uint32_t)f2bf(tile[r2][cp]) | ((uint32_t)f2bf(tile[r2 + 1][cp]) << 16);
    *(uint32_t*)(dst + (size_t)(cb + cp) * R + rbase + r2) = u;
  }
}

// ---------------- GEMM1: 128 rows x 256 B-cols (128 h-cols), BK=64, 8 waves ----------------
__global__ __launch_bounds__(512) void gemm_gu_kernel(
    const uint16_t* __restrict__ xb, const uint16_t* __restrict__ w1t,
    const int* __restrict__ counts, const int* __restrict__ tok_slot,
    uint16_t* __restrict__ h_buf) {
  int id = blockIdx.x;
  id = (id & 7) * 256 + (id >> 3);
  int e = id >> 8;
  int rem = id & 255;
  int rb = rem >> 3;
  int cb = rem & 7;
  int M = counts[e];
  if (rb * 128 >= M) return;
  int c0 = cb * 128;
  const int* list = tok_slot + e * N_TOK;
  const uint16_t* wB = w1t + (size_t)e * TWO_D * HDIM;

  __shared__ uint16_t As[128 * BK];
  __shared__ uint16_t Bs[256 * BK];

  int tid = threadIdx.x;
  int w = tid >> 6, l = tid & 63;
  int wr = w >> 2, wc = w & 3;
  int lane15 = l & 15, hi = l >> 4;

  const char* aSrc[2]; char* aDst[2];
#pragma unroll
  for (int p = 0; p < 2; ++p) {
    int row = p * 64 + (tid >> 3);
    int pos = rb * 128 + row; if (pos > M - 1) pos = M - 1;
    int tok = list[pos] >> 1;
    int kch = (tid & 7) ^ (row & 7);
    aSrc[p] = (const char*)(xb + (size_t)tok * HDIM) + kch * 16;
    aDst[p] = (char*)As + p * 8192 + tid * 16;
  }
  const char* bSrc[4]; char* bDst[4];
#pragma unroll
  for (int p = 0; p < 4; ++p) {
    int s = p * 64 + (tid >> 3);
    int j = s & 63, g = s >> 6;
    int col = (j < 32) ? (c0 + g * 32 + j) : (HDIM + c0 + g * 32 + (j - 32));
    int kch = (tid & 7) ^ (s & 7);
    bSrc[p] = (const char*)(wB + (size_t)col * HDIM) + kch * 16;
    bDst[p] = (char*)Bs + p * 8192 + tid * 16;
  }

  f32x4_t acc[4][4];
#pragma unroll
  for (int m = 0; m < 4; ++m)
#pragma unroll
    for (int n = 0; n < 4; ++n) acc[m][n] = {0.f, 0.f, 0.f, 0.f};

  uint32_t aRow[4], bRow[4], xch[2];
#pragma unroll
  for (int m = 0; m < 4; ++m) aRow[m] = (uint32_t)((wr * 64 + m * 16 + lane15) * 128);
#pragma unroll
  for (int n = 0; n < 4; ++n) bRow[n] = (uint32_t)((wc * 64 + n * 16 + lane15) * 128);
  xch[0] = (uint32_t)(((0 + hi) ^ (l & 7)) * 16);
  xch[1] = (uint32_t)(((4 + hi) ^ (l & 7)) * 16);

#pragma unroll
  for (int p = 0; p < 2; ++p) gload16(aSrc[p], aDst[p]);
#pragma unroll
  for (int p = 0; p < 4; ++p) gload16(bSrc[p], bDst[p]);

  for (int kt = 0; kt < HDIM / BK; ++kt) {
    __syncthreads();
    bf16x8_t a[2][4], b[2][4];
#pragma unroll
    for (int kk = 0; kk < 2; ++kk) {
#pragma unroll
      for (int m = 0; m < 4; ++m)
        a[kk][m] = *(const bf16x8_t*)((const char*)As + aRow[m] + xch[kk]);
#pragma unroll
      for (int n = 0; n < 4; ++n)
        b[kk][n] = *(const bf16x8_t*)((const char*)Bs + bRow[n] + xch[kk]);
    }
    __syncthreads();
    if (kt + 1 < HDIM / BK) {
      int ko = (kt + 1) * 128;
#pragma unroll
      for (int p = 0; p < 2; ++p) gload16(aSrc[p] + ko, aDst[p]);
#pragma unroll
      for (int p = 0; p < 4; ++p) gload16(bSrc[p] + ko, bDst[p]);
    }
#pragma unroll
    for (int kk = 0; kk < 2; ++kk)
#pragma unroll
      for (int m = 0; m < 4; ++m)
#pragma unroll
        for (int n = 0; n < 4; ++n)
          acc[m][n] = __builtin_amdgcn_mfma_f32_16x16x32_bf16(a[kk][m], b[kk][n], acc[m][n], 0, 0, 0);
  }

  int Mloc = M - rb * 128;
#pragma unroll
  for (int m = 0; m < 4; ++m) {
#pragma unroll
    for (int i = 0; i < 4; ++i) {
      int rl = wr * 64 + m * 16 + hi * 4 + i;
      if (rl < Mloc) {
        int slot = list[rb * 128 + rl];
        uint16_t* hr = h_buf + (size_t)slot * DDIM;
#pragma unroll
        for (int n = 0; n < 2; ++n) {
          int hcol = c0 + wc * 32 + n * 16 + lane15;
          float g = acc[m][n][i];
          float u = acc[m][n + 2][i];
          float hv = g / (1.f + expf(-g)) * u;
          hr[hcol] = f2bf(hv);
        }
      }
    }
  }
}

// ---------------- GEMM2: 128 rows x 256 cols, BK=64, 8 waves, atomic-free ----------------
__global__ __launch_bounds__(512) void gemm_down_kernel(
    const uint16_t* __restrict__ h_buf, const uint16_t* __restrict__ w2t,
    const int* __restrict__ counts, const int* __restrict__ tok_slot,
    uint16_t* __restrict__ ob) {
  // grid 1024 = 8 experts x 32 rb x 4 cb ; XCD chunk 128 = 1 expert/XCD
  int id = blockIdx.x;
  id = (id & 7) * 128 + (id >> 3);
  int e = id >> 7;
  int rem = id & 127;
  int rb = rem >> 2;
  int cb = rem & 3;
  int M = counts[e];
  if (rb * 128 >= M) return;
  int c0 = cb * 256;
  const int* list = tok_slot + e * N_TOK;
  const uint16_t* wB = w2t + (size_t)e * HDIM * DDIM;

  __shared__ uint16_t As[128 * BK];  // 16KB
  __shared__ uint16_t Bs[256 * BK];  // 32KB

  int tid = threadIdx.x;
  int w = tid >> 6, l = tid & 63;
  int wr = w >> 2, wc = w & 3;
  int lane15 = l & 15, hi = l >> 4;

  const char* aSrc[2]; char* aDst[2];
#pragma unroll
  for (int p = 0; p < 2; ++p) {
    int row = p * 64 + (tid >> 3);
    int pos = rb * 128 + row; if (pos > M - 1) pos = M - 1;
    int slot = list[pos];
    int kch = (tid & 7) ^ (row & 7);
    aSrc[p] = (const char*)(h_buf + (size_t)slot * DDIM) + kch * 16;
    aDst[p] = (char*)As + p * 8192 + tid * 16;
  }
  const char* bSrc[4]; char* bDst[4];
#pragma unroll
  for (int p = 0; p < 4; ++p) {
    int s = p * 64 + (tid >> 3);
    int col = c0 + s;
    int kch = (tid & 7) ^ (s & 7);
    bSrc[p] = (const char*)(wB + (size_t)col * DDIM) + kch * 16;
    bDst[p] = (char*)Bs + p * 8192 + tid * 16;
  }

  f32x4_t acc[4][4];
#pragma unroll
  for (int m = 0; m < 4; ++m)
#pragma unroll
    for (int n = 0; n < 4; ++n) acc[m][n] = {0.f, 0.f, 0.f, 0.f};

  uint32_t aRow[4], bRow[4], xch[2];
#pragma unroll
  for (int m = 0; m < 4; ++m) aRow[m] = (uint32_t)((wr * 64 + m * 16 + lane15) * 128);
#pragma unroll
  for (int n = 0; n < 4; ++n) bRow[n] = (uint32_t)((wc * 64 + n * 16 + lane15) * 128);
  xch[0] = (uint32_t)(((0 + hi) ^ (l & 7)) * 16);
  xch[1] = (uint32_t)(((4 + hi) ^ (l & 7)) * 16);

#pragma unroll
  for (int p = 0; p < 2; ++p) gload16(aSrc[p], aDst[p]);
#pragma unroll
  for (int p = 0; p < 4; ++p) gload16(bSrc[p], bDst[p]);

  for (int kt = 0; kt < DDIM / BK; ++kt) {
    __syncthreads();
    bf16x8_t a[2][4], b[2][4];
#pragma unroll
    for (int kk = 0; kk < 2; ++kk) {
#pragma unroll
      for (int m = 0; m < 4; ++m)
        a[kk][m] = *(const bf16x8_t*)((const char*)As + aRow[m] + xch[kk]);
#pragma unroll
      for (int n = 0; n < 4; ++n)
        b[kk][n] = *(const bf16x8_t*)((const char*)Bs + bRow[n] + xch[kk]);
    }
    __syncthreads();
    if (kt + 1 < DDIM / BK) {
      int ko = (kt + 1) * 128;
#pragma unroll
      for (int p = 0; p < 2; ++p) gload16(aSrc[p] + ko, aDst[p]);
#pragma unroll
      for (int p = 0; p < 4; ++p) gload16(bSrc[p] + ko, bDst[p]);
    }
#pragma unroll
    for (int kk = 0; kk < 2; ++kk)
#pragma unroll
      for (int m = 0; m < 4; ++m)
#pragma unroll
        for (int n = 0; n < 4; ++n)
          acc[m][n] = __builtin_amdgcn_mfma_f32_16x16x32_bf16(a[kk][m], b[kk][n], acc[m][n], 0, 0, 0);
  }

  int Mloc = M - rb * 128;
#pragma unroll
  for (int m = 0; m < 4; ++m) {
#pragma unroll
    for (int i = 0; i < 4; ++i) {
      int rl = wr * 64 + m * 16 + hi * 4 + i;
      if (rl < Mloc) {
        int slot = list[rb * 128 + rl];
        uint16_t* orow = ob + ((size_t)slot << 10);
#pragma unroll
        for (int n = 0; n < 4; ++n) {
          int col = c0 + wc * 64 + n * 16 + lane15;
          orow[col] = f2bf(acc[m][n][i]);
        }
      }
    }
  }
}

// ---------------- combine: out[t] = w0*ob[2t] + w1*ob[2t+1] ----------------
__global__ __launch_bounds__(256) void combine_kernel(
    const uint16_t* __restrict__ ob, const float* __restrict__ slot_w,
    float* __restrict__ out) {
  int idx = blockIdx.x * 256 + threadIdx.x;  // 8 elements per thread
  int t = idx >> 7;
  int d8 = idx & 127;
  const uint16_t* r0 = ob + ((size_t)(2 * t) << 10) + d8 * 8;
  const uint16_t* r1 = ob + ((size_t)(2 * t + 1) << 10) + d8 * 8;
  float w0 = slot_w[2 * t], w1 = slot_w[2 * t + 1];
  uint4 a = *(const uint4*)r0;
  uint4 b = *(const uint4*)r1;
  float o[8];
  const uint32_t* au = (const uint32_t*)&a;
  const uint32_t* bu = (const uint32_t*)&b;
#pragma unroll
  for (int j = 0; j < 4; ++j) {
    o[2 * j]     = w0 * bf2f((uint16_t)(au[j] & 0xffffu)) + w1 * bf2f((uint16_t)(bu[j] & 0xffffu));
    o[2 * j + 1] = w0 * bf2f((uint16_t)(au[j] >> 16))     + w1 * bf2f((uint16_t)(bu[j] >> 16));
  }
  float4* op = (float4*)(out + (size_t)t * HDIM + d8 * 8);
  op[0] = make_float4(o[0], o[1], o[2], o[3]);
  op[1] = make_float4(o[4], o[5], o[6], o[7]);
}

extern "C" void kernel_launch(void* const* d_in, const int* in_sizes, int n_in,
                              void* d_out, int out_size, void* d_ws, size_t ws_size,
                              hipStream_t stream) {
  const float* x  = (const float*)d_in[0];
  const float* gw = (const float*)d_in[1];
  const float* w1 = (const float*)d_in[2];
  const float* w2 = (const float*)d_in[3];
  float* out = (float*)d_out;

  char* ws = (char*)d_ws;
  int*      counts   = (int*)ws;                               // 1 KB
  int*      tok_slot = (int*)(ws + 1024);                      // 128 KB
  float*    slot_w   = (float*)(ws + 1024 + 131072);           // 32 KB
  uint32_t* t_e      = (uint32_t*)(ws + 1024 + 131072 + 32768);// 16 KB
  size_t off = (size_t)1 << 20;
  uint16_t* xb  = (uint16_t*)(ws + off); off += (size_t)N_TOK * HDIM * 2;        // 8 MB
  uint16_t* w1t = (uint16_t*)(ws + off); off += (size_t)NEXP * TWO_D * HDIM * 2; // 32 MB
  uint16_t* w2t = (uint16_t*)(ws + off); off += (size_t)NEXP * HDIM * DDIM * 2;  // 16 MB
  uint16_t* hb  = (uint16_t*)(ws + off); off += (size_t)2 * N_TOK * DDIM * 2;    // 16 MB
  // ob aliases w1t: w1t is dead after gemm_gu completes (stream-ordered), ob needs 16 MB <= 32 MB
  uint16_t* ob = w1t;

  if (ws_size < off) {
    hipMemsetAsync(d_out, 0, (size_t)out_size * sizeof(float), stream);
    return;
  }

  cvt_x_kernel<<<(N_TOK * HDIM) / 1024, 256, 0, stream>>>(x, xb);
  transpose_cvt_kernel<<<dim3(TWO_D / 32, HDIM / 32, NEXP), 256, 0, stream>>>(w1, w1t, HDIM, TWO_D);
  transpose_cvt_kernel<<<dim3(HDIM / 32, DDIM / 32, NEXP), 256, 0, stream>>>(w2, w2t, DDIM, HDIM);
  router_kernel<<<N_TOK / 4, 256, 0, stream>>>(x, gw, t_e, slot_w);
  build_lists_kernel<<<1, 256, 0, stream>>>(t_e, counts, tok_slot);
  gemm_gu_kernel<<<2048, 512, 0, stream>>>(xb, w1t, counts, tok_slot, hb);
  gemm_down_kernel<<<1024, 512, 0, stream>>>(hb, w2t, counts, tok_slot, ob);
  combine_kernel<<<(N_TOK * HDIM / 8) / 256, 256, 0, stream>>>(ob, slot_w, out);
}